// Round 1
// baseline (97.062 us; speedup 1.0000x reference)
//
#include <hip/hip_runtime.h>
#include <math.h>

#define Bdim 16
#define Tdim 1024
#define Vdim 2048
#define FEAT (2 * Vdim + 4)   // 4100
#define CONF_THR 0.55f

struct RunMeta {
    int start;
    int end;        // one past last valid frame
    float m;        // scale / gate_sum
    float e0, e1, e2, e3;  // pre-scaled extras: seg_conf, s_lab_mean, left_b, right_b (all * scale)
    float pad;
};  // 32 bytes

// -------- Phase 1: per-batch run segmentation + metadata (1 block per batch) --------
__global__ __launch_bounds__(1024) void phase1_kernel(
    const float* __restrict__ shallow, const float* __restrict__ final_,
    const float* __restrict__ boundary, const int* __restrict__ align,
    const int* __restrict__ lengths,
    float* __restrict__ gate_ws, RunMeta* __restrict__ meta, int* __restrict__ nseg_ws,
    float* __restrict__ out_conf, float* __restrict__ out_len)
{
    __shared__ int   s_runid[Tdim];
    __shared__ int   s_scan[Tdim];
    __shared__ int   s_lab[Tdim];
    __shared__ float s_gate[Tdim];
    __shared__ float s_fc[Tdim];
    __shared__ float s_slab[Tdim];
    __shared__ int   r_cnt[Tdim];
    __shared__ int   r_start[Tdim];
    __shared__ int   r_end[Tdim];
    __shared__ int   r_label[Tdim];
    __shared__ float r_gsum[Tdim];
    __shared__ float r_fcsum[Tdim];
    __shared__ float r_ssum[Tdim];
    __shared__ float s_conf[Tdim];

    const int b = blockIdx.x;
    const int t = threadIdx.x;
    const int length = lengths[b];
    const bool valid = (t < length);
    const int lab = valid ? align[b * Tdim + t] : 0;
    s_lab[t] = lab;

    // per-frame label confidences (gathered scalar loads)
    const size_t rowoff = ((size_t)(b * Tdim) + t) * Vdim;
    const float sv = shallow[rowoff + lab];
    const float fv = final_[rowoff + lab];
    const float fc = 0.5f * (sv + fv);
    float gate = 0.0f;
    if (valid) gate = 1.0f / (1.0f + expf(-(fc - CONF_THR) * 12.0f)) + 0.05f;
    s_gate[t] = gate;
    s_fc[t]   = fc;
    s_slab[t] = sv;
    __syncthreads();

    // change flags + inclusive scan -> run id
    const int change = (t == 0) ? 1 : (s_lab[t] != s_lab[t - 1] ? 1 : 0);
    s_scan[t] = change;
    __syncthreads();
    for (int off = 1; off < Tdim; off <<= 1) {
        int v = s_scan[t];
        int add = (t >= off) ? s_scan[t - off] : 0;
        __syncthreads();
        s_scan[t] = v + add;
        __syncthreads();
    }
    const int runid = s_scan[t] - 1;
    s_runid[t] = runid;
    r_cnt[t] = 0;
    s_conf[t] = 0.0f;
    __syncthreads();

    // run leaders walk their (contiguous) run deterministically
    if (valid && change) {
        float gs = 0.f, fs = 0.f, ss = 0.f;
        int f = t;
        while (f < length && s_runid[f] == runid) {
            gs += s_gate[f];
            fs += s_fc[f];
            ss += s_slab[f];
            ++f;
        }
        r_cnt[runid]   = f - t;
        r_start[runid] = t;
        r_end[runid]   = f;
        r_label[runid] = s_lab[t];
        r_gsum[runid]  = gs;
        r_fcsum[runid] = fs;
        r_ssum[runid]  = ss;
    }
    __syncthreads();

    // per-run: valid (nonblank) flag + rank scan
    const int cnt = r_cnt[t];
    const int vr = (cnt > 0 && r_label[t] != 0) ? 1 : 0;
    s_scan[t] = vr;
    __syncthreads();
    for (int off = 1; off < Tdim; off <<= 1) {
        int v = s_scan[t];
        int add = (t >= off) ? s_scan[t - off] : 0;
        __syncthreads();
        s_scan[t] = v + add;
        __syncthreads();
    }
    const int rank = s_scan[t] - 1;
    const int nseg = s_scan[Tdim - 1];

    if (vr) {
        const int start = r_start[t];
        const int endp  = r_end[t];
        int li = start - 1; if (li < 0) li = 0;
        const float left_b  = (rank == 0) ? 1.0f : boundary[b * Tdim + li];
        const float right_b = boundary[b * Tdim + (endp - 1)];
        const float scale = 1.0f + 0.25f * (1.0f - left_b) + 0.25f * (1.0f - right_b);
        const float seg_conf  = r_fcsum[t] / (float)cnt;
        const float slab_mean = r_ssum[t] / (float)cnt;
        const float gsum = fmaxf(r_gsum[t], 1e-6f);
        RunMeta mm;
        mm.start = start;
        mm.end = endp;
        mm.m = scale / gsum;
        mm.e0 = seg_conf * scale;
        mm.e1 = slab_mean * scale;
        mm.e2 = left_b * scale;
        mm.e3 = right_b * scale;
        mm.pad = 0.f;
        meta[b * Tdim + rank] = mm;
        float c = seg_conf;
        c = fminf(fmaxf(c, 0.05f), 1.0f);
        s_conf[rank] = c;
    }
    __syncthreads();
    if (t == 0) {
        if (nseg == 0) s_conf[0] = 1.0f;
        nseg_ws[b] = nseg;
        out_len[b] = (float)(nseg > 0 ? nseg : 1);
    }
    __syncthreads();
    out_conf[b * Tdim + t] = s_conf[t];
    gate_ws[b * Tdim + t] = gate;
}

// -------- Phase 2: pooled feature rows (1 block per output row) --------
__global__ __launch_bounds__(256) void phase2_kernel(
    const float* __restrict__ shallow, const float* __restrict__ final_,
    const float* __restrict__ gate_ws, const RunMeta* __restrict__ meta,
    const int* __restrict__ nseg_ws, float* __restrict__ padded)
{
    const int row = blockIdx.x;
    const int b = row >> 10;
    const int r = row & (Tdim - 1);
    const int tid = threadIdx.x;
    float* out = padded + (size_t)row * FEAT;
    const int ns = nseg_ws[b];

    if (r >= ns) {
        float4 z = make_float4(0.f, 0.f, 0.f, 0.f);
        float4* o4 = (float4*)out;
        #pragma unroll
        for (int i = 0; i < 4; ++i) o4[tid + 256 * i] = z;
        if (tid == 0) o4[1024] = z;
        return;
    }

    const RunMeta mm = meta[row];
    float4 aS0 = make_float4(0.f,0.f,0.f,0.f), aS1 = aS0, aF0 = aS0, aF1 = aS0;
    const float4* sB = (const float4*)(shallow + (size_t)b * Tdim * Vdim);
    const float4* fB = (const float4*)(final_  + (size_t)b * Tdim * Vdim);

    for (int f = mm.start; f < mm.end; ++f) {
        const float g = gate_ws[b * Tdim + f];
        const float4* srow = sB + (size_t)f * (Vdim / 4);
        const float4* frow = fB + (size_t)f * (Vdim / 4);
        float4 s0 = srow[tid];
        float4 s1 = srow[tid + 256];
        float4 f0 = frow[tid];
        float4 f1 = frow[tid + 256];
        aS0.x += s0.x * g; aS0.y += s0.y * g; aS0.z += s0.z * g; aS0.w += s0.w * g;
        aS1.x += s1.x * g; aS1.y += s1.y * g; aS1.z += s1.z * g; aS1.w += s1.w * g;
        aF0.x += f0.x * g; aF0.y += f0.y * g; aF0.z += f0.z * g; aF0.w += f0.w * g;
        aF1.x += f1.x * g; aF1.y += f1.y * g; aF1.z += f1.z * g; aF1.w += f1.w * g;
    }

    const float m = mm.m;
    float4* o4 = (float4*)out;
    o4[tid]        = make_float4(aS0.x * m, aS0.y * m, aS0.z * m, aS0.w * m);
    o4[tid + 256]  = make_float4(aS1.x * m, aS1.y * m, aS1.z * m, aS1.w * m);
    o4[tid + 512]  = make_float4(aF0.x * m, aF0.y * m, aF0.z * m, aF0.w * m);
    o4[tid + 768]  = make_float4(aF1.x * m, aF1.y * m, aF1.z * m, aF1.w * m);
    if (tid < 4) out[4096 + tid] = (&mm.e0)[tid];
}

extern "C" void kernel_launch(void* const* d_in, const int* in_sizes, int n_in,
                              void* d_out, int out_size, void* d_ws, size_t ws_size,
                              hipStream_t stream) {
    const float* shallow  = (const float*)d_in[0];
    const float* final_   = (const float*)d_in[1];
    const float* boundary = (const float*)d_in[2];
    const int*   align    = (const int*)d_in[3];
    const int*   lengths  = (const int*)d_in[4];

    float* out = (float*)d_out;
    float* padded   = out;                                       // [B, T, FEAT]
    float* out_len  = out + (size_t)Bdim * Tdim * FEAT;          // [B]
    float* out_conf = out_len + Bdim;                            // [B, T]

    // workspace layout (tight): gate [B*T] f32, nseg [B] i32, meta [B*T] RunMeta
    char* ws = (char*)d_ws;
    float* gate_ws = (float*)ws;                                  // 65536 B
    int* nseg_ws = (int*)(ws + (size_t)Bdim * Tdim * sizeof(float));
    size_t meta_off = (size_t)Bdim * Tdim * sizeof(float) + 256;  // nseg padded to 256B
    RunMeta* meta = (RunMeta*)(ws + meta_off);                    // 512 KiB

    phase1_kernel<<<Bdim, Tdim, 0, stream>>>(shallow, final_, boundary, align, lengths,
                                             gate_ws, meta, nseg_ws, out_conf, out_len);
    phase2_kernel<<<Bdim * Tdim, 256, 0, stream>>>(shallow, final_, gate_ws, meta,
                                                   nseg_ws, padded);
}

// Round 3
// 75.641 us; speedup vs baseline: 1.2832x; 1.2832x over previous
//
#include <hip/hip_runtime.h>
#include <math.h>

#define Bdim 16
#define Tdim 1024
#define Vdim 2048
#define FEAT (2 * Vdim + 4)   // 4100
#define CONF_THR 0.55f

typedef float f32x4 __attribute__((ext_vector_type(4)));

struct RunMeta {
    int start;
    int end;               // one past last valid frame
    float m;               // scale / gate_sum
    float e0, e1, e2, e3;  // pre-scaled extras: seg_conf, s_lab_mean, left_b, right_b (all * scale)
    float pad;
};  // 32 bytes

// -------- Phase 1: per-batch run segmentation + metadata (1 block per batch) --------
// Ballot-based scans: ~6 barriers total (vs ~40 for Hillis-Steele).
__global__ __launch_bounds__(1024) void phase1_kernel(
    const float* __restrict__ shallow, const float* __restrict__ final_,
    const float* __restrict__ boundary, const int* __restrict__ align,
    const int* __restrict__ lengths,
    float* __restrict__ gate_ws, RunMeta* __restrict__ meta, int* __restrict__ nseg_ws,
    float* __restrict__ out_conf, float* __restrict__ out_len)
{
    __shared__ int   s_lab[Tdim];
    __shared__ unsigned char s_change[Tdim];
    __shared__ float s_gate[Tdim];
    __shared__ float s_fc[Tdim];
    __shared__ float s_slab[Tdim];
    __shared__ int   wsum[16];
    __shared__ int   woff[16];
    __shared__ int   s_nseg;
    __shared__ int   r_start[Tdim];
    __shared__ int   r_end[Tdim];
    __shared__ int   r_label[Tdim];
    __shared__ int   r_cnt[Tdim];
    __shared__ float r_gsum[Tdim];
    __shared__ float r_fcsum[Tdim];
    __shared__ float r_ssum[Tdim];
    __shared__ float s_conf[Tdim];

    const int b = blockIdx.x;
    const int t = threadIdx.x;
    const int lane = t & 63;
    const int wid  = t >> 6;
    const int length = lengths[b];
    const bool valid = (t < length);
    const int lab = valid ? align[b * Tdim + t] : 0;
    s_lab[t] = lab;
    r_cnt[t] = 0;
    s_conf[t] = 0.0f;

    // issue the gathered confidence loads early; latency overlaps the scan below
    const size_t rowoff = ((size_t)(b * Tdim) + t) * Vdim;
    const float sv = shallow[rowoff + lab];
    const float fv = final_[rowoff + lab];
    __syncthreads();

    // change flags + block-wide inclusive scan via ballot + wave-offset scan
    const int change = (t == 0) ? 1 : (lab != s_lab[t - 1] ? 1 : 0);
    s_change[t] = (unsigned char)change;
    {
        unsigned long long bal = __ballot(change);
        int wprefix = __popcll(bal & ((~0ULL) >> (63 - lane)));   // inclusive within wave
        if (lane == 63) wsum[wid] = wprefix;

        const float fc = 0.5f * (sv + fv);
        float gate = 0.0f;
        if (valid) gate = 1.0f / (1.0f + __expf(-(fc - CONF_THR) * 12.0f)) + 0.05f;
        s_gate[t] = gate;
        s_fc[t]   = fc;
        s_slab[t] = sv;
        __syncthreads();
        if (t == 0) {
            int run = 0;
            #pragma unroll
            for (int i = 0; i < 16; ++i) { woff[i] = run; run += wsum[i]; }
        }
        __syncthreads();
        const int runid = woff[wid] + wprefix - 1;

        // run leaders walk their (contiguous, short) run deterministically
        if (change && valid) {
            float gs = gate, fs = fc, ss = sv;
            int f = t + 1;
            while (f < length && !s_change[f]) {
                gs += s_gate[f]; fs += s_fc[f]; ss += s_slab[f]; ++f;
            }
            r_start[runid] = t;
            r_end[runid]   = f;
            r_label[runid] = lab;
            r_gsum[runid]  = gs;
            r_fcsum[runid] = fs;
            r_ssum[runid]  = ss;
            r_cnt[runid]   = f - t;
        }
    }
    __syncthreads();

    // rank scan over nonblank runs (t = run index)
    const int cnt = r_cnt[t];
    const int vr = (cnt > 0 && r_label[t] != 0) ? 1 : 0;
    unsigned long long bal2 = __ballot(vr);
    int wp2 = __popcll(bal2 & ((~0ULL) >> (63 - lane)));
    if (lane == 63) wsum[wid] = wp2;
    __syncthreads();
    if (t == 0) {
        int run = 0;
        #pragma unroll
        for (int i = 0; i < 16; ++i) { woff[i] = run; run += wsum[i]; }
        s_nseg = run;
    }
    __syncthreads();
    const int rank = woff[wid] + wp2 - 1;
    const int nseg = s_nseg;

    if (vr) {
        const int start = r_start[t];
        const int endp  = r_end[t];
        int li = start - 1; if (li < 0) li = 0;
        const float left_b  = (rank == 0) ? 1.0f : boundary[b * Tdim + li];
        const float right_b = boundary[b * Tdim + (endp - 1)];
        const float scale = 1.0f + 0.25f * (1.0f - left_b) + 0.25f * (1.0f - right_b);
        const float seg_conf  = r_fcsum[t] / (float)cnt;
        const float slab_mean = r_ssum[t] / (float)cnt;
        const float gsum = fmaxf(r_gsum[t], 1e-6f);
        RunMeta mm;
        mm.start = start;
        mm.end = endp;
        mm.m = scale / gsum;
        mm.e0 = seg_conf * scale;
        mm.e1 = slab_mean * scale;
        mm.e2 = left_b * scale;
        mm.e3 = right_b * scale;
        mm.pad = 0.f;
        meta[b * Tdim + rank] = mm;
        s_conf[rank] = fminf(fmaxf(seg_conf, 0.05f), 1.0f);
    }
    __syncthreads();
    if (t == 0) {
        if (nseg == 0) s_conf[0] = 1.0f;
        nseg_ws[b] = nseg;
        out_len[b] = (float)(nseg > 0 ? nseg : 1);
    }
    __syncthreads();
    out_conf[b * Tdim + t] = s_conf[t];
    gate_ws[b * Tdim + t] = s_gate[t];
}

// -------- Phase 2: pooled feature rows (1024-thread block = 4 rows, 256 threads each) --------
__global__ __launch_bounds__(1024) void phase2_kernel(
    const float* __restrict__ shallow, const float* __restrict__ final_,
    const float* __restrict__ gate_ws, const RunMeta* __restrict__ meta,
    const int* __restrict__ nseg_ws, float* __restrict__ padded)
{
    const int tid = threadIdx.x & 255;
    const int sub = threadIdx.x >> 8;
    const int row = blockIdx.x * 4 + sub;
    const int b = row >> 10;
    const int r = row & (Tdim - 1);
    float* out = padded + (size_t)row * FEAT;
    f32x4* o4 = (f32x4*)out;
    const int ns = nseg_ws[b];

    if (r >= ns) {
        const f32x4 z = (f32x4)(0.f);
        #pragma unroll
        for (int i = 0; i < 4; ++i)
            __builtin_nontemporal_store(z, o4 + tid + 256 * i);
        if (tid == 0) __builtin_nontemporal_store(z, o4 + 1024);
        return;
    }

    const RunMeta mm = meta[row];
    f32x4 aS0 = (f32x4)(0.f), aS1 = (f32x4)(0.f), aF0 = (f32x4)(0.f), aF1 = (f32x4)(0.f);
    const f32x4* sB = (const f32x4*)(shallow + (size_t)b * Tdim * Vdim);
    const f32x4* fB = (const f32x4*)(final_  + (size_t)b * Tdim * Vdim);

    for (int f = mm.start; f < mm.end; ++f) {
        const float g = gate_ws[b * Tdim + f];
        const f32x4* srow = sB + (size_t)f * (Vdim / 4);
        const f32x4* frow = fB + (size_t)f * (Vdim / 4);
        f32x4 s0 = srow[tid];
        f32x4 s1 = srow[tid + 256];
        f32x4 f0 = frow[tid];
        f32x4 f1 = frow[tid + 256];
        aS0 += s0 * g;
        aS1 += s1 * g;
        aF0 += f0 * g;
        aF1 += f1 * g;
    }

    const float m = mm.m;
    __builtin_nontemporal_store(aS0 * m, o4 + tid);
    __builtin_nontemporal_store(aS1 * m, o4 + tid + 256);
    __builtin_nontemporal_store(aF0 * m, o4 + tid + 512);
    __builtin_nontemporal_store(aF1 * m, o4 + tid + 768);
    if (tid < 4) __builtin_nontemporal_store((&mm.e0)[tid], out + 4096 + tid);
}

extern "C" void kernel_launch(void* const* d_in, const int* in_sizes, int n_in,
                              void* d_out, int out_size, void* d_ws, size_t ws_size,
                              hipStream_t stream) {
    const float* shallow  = (const float*)d_in[0];
    const float* final_   = (const float*)d_in[1];
    const float* boundary = (const float*)d_in[2];
    const int*   align    = (const int*)d_in[3];
    const int*   lengths  = (const int*)d_in[4];

    float* out = (float*)d_out;
    float* padded   = out;                                       // [B, T, FEAT]
    float* out_len  = out + (size_t)Bdim * Tdim * FEAT;          // [B]
    float* out_conf = out_len + Bdim;                            // [B, T]

    // workspace layout: gate [B*T] f32, nseg [B] i32 (padded), meta [B*T] RunMeta
    char* ws = (char*)d_ws;
    float* gate_ws = (float*)ws;                                  // 64 KiB
    int* nseg_ws = (int*)(ws + (size_t)Bdim * Tdim * sizeof(float));
    size_t meta_off = (size_t)Bdim * Tdim * sizeof(float) + 256;
    RunMeta* meta = (RunMeta*)(ws + meta_off);                    // 512 KiB

    phase1_kernel<<<Bdim, Tdim, 0, stream>>>(shallow, final_, boundary, align, lengths,
                                             gate_ws, meta, nseg_ws, out_conf, out_len);
    phase2_kernel<<<(Bdim * Tdim) / 4, 1024, 0, stream>>>(shallow, final_, gate_ws, meta,
                                                          nseg_ws, padded);
}

// Round 4
// 66.674 us; speedup vs baseline: 1.4558x; 1.1345x over previous
//
#include <hip/hip_runtime.h>
#include <math.h>

#define Bdim 16
#define Tdim 1024
#define Vdim 2048
#define FEAT (2 * Vdim + 4)   // 4100
#define CONF_THR 0.55f

typedef float f32x4 __attribute__((ext_vector_type(4)));

// One block per output row (b, r). The block recomputes its batch's run
// structure from the 4KB align row (L2-hot), selects the r-th nonblank run
// via bitmask popcount/ffs (uniform across the block), then streams the run's
// frames of shallow/final with gated accumulation. Per-frame label
// confidences come from same-address broadcast loads of lines the block is
// already streaming (zero extra HBM traffic). All per-run scalars are
// computed redundantly by every thread -> no reductions, 2 barriers total.
__global__ __launch_bounds__(256) void fused_kernel(
    const float* __restrict__ shallow, const float* __restrict__ final_,
    const float* __restrict__ boundary, const int* __restrict__ align,
    const int* __restrict__ lengths,
    float* __restrict__ padded, float* __restrict__ out_len, float* __restrict__ out_conf)
{
    __shared__ int s_lab[Tdim];          // 4 KiB
    __shared__ unsigned int s_chg[32];   // change-flag bitmask over t
    __shared__ unsigned int s_nb[32];    // nonblank-run-start bitmask over t

    const int row = blockIdx.x;
    const int b = row >> 10;
    const int r = row & (Tdim - 1);
    const int tid = threadIdx.x;
    const int length = lengths[b];

    if (tid < 32) { s_chg[tid] = 0u; s_nb[tid] = 0u; }

    // 4 labels per thread, masked to blank beyond length
    const int4 l4 = ((const int4*)(align + b * Tdim))[tid];
    const int t0 = tid * 4;
    const int la0 = (t0 + 0 < length) ? l4.x : 0;
    const int la1 = (t0 + 1 < length) ? l4.y : 0;
    const int la2 = (t0 + 2 < length) ? l4.z : 0;
    const int la3 = (t0 + 3 < length) ? l4.w : 0;
    s_lab[t0 + 0] = la0; s_lab[t0 + 1] = la1;
    s_lab[t0 + 2] = la2; s_lab[t0 + 3] = la3;
    __syncthreads();

    const int prev = (tid == 0) ? -1 : s_lab[t0 - 1];   // labels >= 0 -> t=0 is always a change
    const unsigned c0 = (la0 != prev) ? 1u : 0u;
    const unsigned c1 = (la1 != la0) ? 1u : 0u;
    const unsigned c2 = (la2 != la1) ? 1u : 0u;
    const unsigned c3 = (la3 != la2) ? 1u : 0u;
    const unsigned chg = c0 | (c1 << 1) | (c2 << 2) | (c3 << 3);
    const unsigned nb = (c0 && la0 ? 1u : 0u) | ((c1 && la1 ? 1u : 0u) << 1)
                      | ((c2 && la2 ? 1u : 0u) << 2) | ((c3 && la3 ? 1u : 0u) << 3);
    const unsigned sh = (tid & 7) * 4;   // bit (4*tid+j) lives in word tid/8 at offset (tid&7)*4+j
    if (chg) atomicOr(&s_chg[tid >> 3], chg << sh);
    if (nb)  atomicOr(&s_nb[tid >> 3],  nb << sh);
    __syncthreads();

    // nseg (redundant on all threads)
    int nseg = 0;
    #pragma unroll
    for (int w = 0; w < 32; ++w) nseg += __popc(s_nb[w]);

    float* out = padded + (size_t)row * FEAT;
    f32x4* o4 = (f32x4*)out;

    if (r >= nseg) {
        const f32x4 z = (f32x4)(0.f);
        #pragma unroll
        for (int i = 0; i < 4; ++i)
            __builtin_nontemporal_store(z, o4 + tid + 256 * i);
        if (tid == 0) {
            __builtin_nontemporal_store(z, o4 + 1024);
            out_conf[row] = (r == 0 && nseg == 0) ? 1.0f : 0.0f;
            if (r == 0) out_len[b] = 1.0f;   // nseg==0 fallback (r==0 lands here only then)
        }
        return;
    }

    // start = position of the (r+1)-th set bit in s_nb (uniform, redundant)
    int start;
    {
        int need = r;
        int w = 0;
        for (; w < 32; ++w) {
            const int c = __popc(s_nb[w]);
            if (need < c) break;
            need -= c;
        }
        unsigned word = s_nb[w];
        for (int k = 0; k < need; ++k) word &= word - 1;
        start = w * 32 + __ffs(word) - 1;
    }
    // end = first change strictly after start (else Tdim)
    int end = Tdim;
    {
        const int p = start + 1;
        int w = p >> 5;
        if (w < 32) {
            unsigned word = s_chg[w] & (0xFFFFFFFFu << (p & 31));
            while (word == 0u && ++w < 32) word = s_chg[w];
            if (word) end = w * 32 + __ffs(word) - 1;
        }
    }

    const int lab = s_lab[start];
    const int cnt = end - start;
    const float left_b  = (r == 0) ? 1.0f : boundary[b * Tdim + start - 1];
    const float right_b = boundary[b * Tdim + end - 1];
    const float scale = 1.0f + 0.25f * (1.0f - left_b) + 0.25f * (1.0f - right_b);

    f32x4 aS0 = (f32x4)(0.f), aS1 = (f32x4)(0.f), aF0 = (f32x4)(0.f), aF1 = (f32x4)(0.f);
    float gsum = 0.f, fcsum = 0.f, ssum = 0.f;
    const float* sRow = shallow + ((size_t)(b * Tdim) + start) * Vdim;
    const float* fRow = final_  + ((size_t)(b * Tdim) + start) * Vdim;

    for (int f = 0; f < cnt; ++f) {
        const f32x4* s4 = (const f32x4*)sRow;
        const f32x4* f4 = (const f32x4*)fRow;
        const float sv = sRow[lab];         // same-address broadcast, line is streamed anyway
        const float fv = fRow[lab];
        const f32x4 s0 = s4[tid];
        const f32x4 s1 = s4[tid + 256];
        const f32x4 f0 = f4[tid];
        const f32x4 f1 = f4[tid + 256];
        const float fc = 0.5f * (sv + fv);
        const float g = 1.0f / (1.0f + __expf(-(fc - CONF_THR) * 12.0f)) + 0.05f;
        gsum += g; fcsum += fc; ssum += sv;
        aS0 += s0 * g; aS1 += s1 * g; aF0 += f0 * g; aF1 += f1 * g;
        sRow += Vdim; fRow += Vdim;
    }

    const float m = scale / fmaxf(gsum, 1e-6f);
    __builtin_nontemporal_store(aS0 * m, o4 + tid);
    __builtin_nontemporal_store(aS1 * m, o4 + tid + 256);
    __builtin_nontemporal_store(aF0 * m, o4 + tid + 512);
    __builtin_nontemporal_store(aF1 * m, o4 + tid + 768);
    if (tid == 0) {
        const float inv_cnt = 1.0f / (float)cnt;
        const float seg_conf = fcsum * inv_cnt;
        f32x4 e;
        e.x = seg_conf * scale;
        e.y = (ssum * inv_cnt) * scale;
        e.z = left_b * scale;
        e.w = right_b * scale;
        __builtin_nontemporal_store(e, o4 + 1024);
        out_conf[row] = fminf(fmaxf(seg_conf, 0.05f), 1.0f);
        if (r == 0) out_len[b] = (float)nseg;
    }
}

extern "C" void kernel_launch(void* const* d_in, const int* in_sizes, int n_in,
                              void* d_out, int out_size, void* d_ws, size_t ws_size,
                              hipStream_t stream) {
    const float* shallow  = (const float*)d_in[0];
    const float* final_   = (const float*)d_in[1];
    const float* boundary = (const float*)d_in[2];
    const int*   align    = (const int*)d_in[3];
    const int*   lengths  = (const int*)d_in[4];

    float* out = (float*)d_out;
    float* padded   = out;                                       // [B, T, FEAT]
    float* out_len  = out + (size_t)Bdim * Tdim * FEAT;          // [B]
    float* out_conf = out_len + Bdim;                            // [B, T]

    fused_kernel<<<Bdim * Tdim, 256, 0, stream>>>(shallow, final_, boundary, align,
                                                  lengths, padded, out_len, out_conf);
}